// Round 11
// baseline (217.154 us; speedup 1.0000x reference)
//
#include <hip/hip_runtime.h>

// Problem constants (match reference)
#define B_   16
#define N_   65536
#define G_   64
#define M_   (N_ + G_)       // 65600 rois per batch
#define R_   128             // ROIS_PER_IMAGE
#define FGP  32              // FG_PER_IMAGE
#define NB_  4096            // buckets over u_perm in [0,1)
#define NROW_ 32             // (batch, class) rows
#define FW_  (NB_ / 32)      // flag words per row = 128
#define TPB_  256

// ---------------------------------------------------------------------------
// K0: zero hist (512 KB); GT table (poisoned gt_zero rows) + jmax.
// ---------------------------------------------------------------------------
__global__ void prep_kernel(const float* __restrict__ gt_boxes,
                            int*    __restrict__ hist,
                            float4* __restrict__ gt4,
                            float*  __restrict__ garea,
                            int*    __restrict__ jmax)
{
    const int gid = blockIdx.x * blockDim.x + threadIdx.x;
    for (int idx = gid; idx < NROW_ * NB_; idx += gridDim.x * blockDim.x) hist[idx] = 0;
    if (gid < B_ * G_) {
        int b = gid >> 6, j = gid & 63;
        const float* g = gt_boxes + gid * 6;
        float x1 = g[0], y1 = g[1], x2 = g[2], y2 = g[3];
        float gw = x2 - x1 + 1.0f, gh = y2 - y1 + 1.0f;
        bool gz = (gw == 1.0f) && (gh == 1.0f);
        gt4[gid] = gz ? make_float4(3.0e8f, 3.0e8f, -3.0e8f, -3.0e8f)
                      : make_float4(x1, y1, x2, y2);
        garea[gid] = gw * gh;                     // == 1.0 for gz rows
        unsigned long long alive = __ballot(!gz); // lane == j
        if (j == 0) { int last = 63 - __clzll(alive); jmax[b] = (last + 8) & ~7; }
    }
}

// ---------------------------------------------------------------------------
// K1: per-roi rational IoU max. Track (ib, sb) with s = (area_a + ga);
//     t = i/s and q = i/(s-i) are order-equivalent (q = t/(1-t)), and the
//     cross-product predicate i1*s2 > i2*s1 is the SAME rational predicate
//     as the uni-form -- decided exactly via Dekker two-product lex compare.
//     Final best = ib/(sb - ib) reproduces reference association bit-exactly:
//     ref uni = (area_a + ga) - inter.  One IEEE divide per thread.
// ---------------------------------------------------------------------------
__global__ void iou_kernel(const float* __restrict__ all_rois,
                           const float* __restrict__ gt_boxes,
                           const float4* __restrict__ gt4,
                           const float*  __restrict__ garea,
                           const int*    __restrict__ jmax,
                           const float*  __restrict__ u_perm,
                           unsigned*     __restrict__ packed,
                           int*          __restrict__ hist)
{
    __shared__ float4 sg[G_];
    __shared__ float  sa[G_];
    const int b   = blockIdx.y;
    const int tid = threadIdx.x;
    if (tid < G_) { sg[tid] = gt4[b * G_ + tid]; sa[tid] = garea[b * G_ + tid]; }
    __syncthreads();

    const int i = blockIdx.x * blockDim.x + tid;
    if (i >= M_) return;

    float x1, y1, x2, y2;
    if (i < N_) {
        const float* p = all_rois + ((size_t)b * N_ + i) * 5;
        x1 = p[1]; y1 = p[2]; x2 = p[3]; y2 = p[4];
    } else {
        const float* p = gt_boxes + (b * G_ + (i - N_)) * 6;
        x1 = p[0]; y1 = p[1]; x2 = p[2]; y2 = p[3];
    }
    float aw = x2 - x1 + 1.0f, ah = y2 - y1 + 1.0f;
    float area_a = aw * ah;
    bool  a_zero = (aw == 1.0f) && (ah == 1.0f);

    const int jm = jmax[b];
    float ib = 0.0f, sb = 1.0f;              // rational best t = 0/1
    for (int jj = 0; jj < jm; jj += 8) {
        #pragma unroll
        for (int kk = 0; kk < 8; ++kk) {
            const int j = jj + kk;
            const float4 g  = sg[j];
            const float  ga = sa[j];
            float iw  = fmaxf(fminf(x2, g.z) - fmaxf(x1, g.x) + 1.0f, 0.0f);
            float ih2 = fmaxf(fminf(y2, g.w) - fmaxf(y1, g.y) + 1.0f, 0.0f);
            float inter = iw * ih2;
            float s     = area_a + ga;                // ref: (area_a+ga) first
            float hi1 = inter * sb, lo1 = fmaf(inter, sb, -hi1);
            float hi2 = ib * s,     lo2 = fmaf(ib, s, -hi2);
            bool gt = (hi1 > hi2) || ((hi1 == hi2) && (lo1 > lo2));  // exact
            if (gt) { ib = inter; sb = s; }           // strict >: first wins
        }
    }
    float best = ib / (sb - ib);  // == ref fl(fl(sb - ib)) then divide, bit-exact
    if (a_zero) best = -1.0f;

    bool fg = best >= 0.7f;
    bool bg = best < 0.3f;        // == ((mo<0.3)&(mo>=0)) | (mo<0)
    unsigned pk = 0xFFFFFFFFu;
    if (fg || bg) {
        int cls = fg ? 0 : 1;
        float u = u_perm[(size_t)b * M_ + i];
        int bucket = min(max((int)(u * (float)NB_), 0), NB_ - 1);
        pk = ((unsigned)cls << 16) | (unsigned)bucket;
        atomicAdd(&hist[(size_t)(b * 2 + cls) * NB_ + bucket], 1);
    }
    packed[(size_t)b * M_ + i] = pk;
}

// ---------------------------------------------------------------------------
// K2: 16 blocks x 1024 threads. Lower 512 threads scan row 2b (fg), upper 512
//     scan row 2b+1 (bg) CONCURRENTLY: 8 bins/thread, wave shfl scan, 8-wave
//     combine per row. Full exclusive prefix kept in LDS (32 KB) AND written
//     to global (for scatter). Then flags zero'd+set and picks computed with
//     a 12-step LDS binsearch. One dispatch, no coarse table.
// ---------------------------------------------------------------------------
__global__ __launch_bounds__(1024) void scanflag_kernel(
    int*      __restrict__ hist,     // counts -> exclusive prefix (in place)
    unsigned* __restrict__ flags,
    const float* __restrict__ u_fg,
    const float* __restrict__ u_bg,
    int4*     __restrict__ pick)
{
    __shared__ int spfx[2][NB_];     // 32 KB
    __shared__ int swt[2][8], swb[2][8];
    __shared__ int scnt[2];
    const int bb  = blockIdx.x;      // batch
    const int tid = threadIdx.x;     // 0..1023
    const int rr  = tid >> 9;        // row half (0 = fg, 1 = bg)
    const int t   = tid & 511;       // position within row
    const int lane = tid & 63, w = (tid >> 6) & 7;

    if (tid < 2 * FW_) flags[bb * 2 * FW_ + tid] = 0;   // own batch's flag words

    const int row = bb * 2 + rr;
    int* h = hist + (size_t)row * NB_ + t * 8;
    int4* h4 = (int4*)h;
    int v[8];
    {
        int4 x4 = h4[0];
        v[0] = x4.x; v[1] = x4.y; v[2] = x4.z; v[3] = x4.w;
        x4 = h4[1];
        v[4] = x4.x; v[5] = x4.y; v[6] = x4.z; v[7] = x4.w;
    }
    int run = 0;
    #pragma unroll
    for (int k = 0; k < 8; ++k) { int x = v[k]; v[k] = run; run += x; }
    int x = run;                                   // wave inclusive scan
    #pragma unroll
    for (int d = 1; d < 64; d <<= 1) {
        int y = __shfl_up(x, d);
        if (lane >= d) x += y;
    }
    if (lane == 63) swt[rr][w] = x;
    __syncthreads();
    if ((tid & 511) == 0) {
        int a = 0;
        #pragma unroll
        for (int q = 0; q < 8; ++q) { swb[rr][q] = a; a += swt[rr][q]; }
        scnt[rr] = a;
    }
    __syncthreads();
    const int texcl = swb[rr][w] + x - run;        // thread-exclusive base
    int e[8];
    #pragma unroll
    for (int k = 0; k < 8; ++k) { e[k] = texcl + v[k]; spfx[rr][t * 8 + k] = e[k]; }
    h4[0] = make_int4(e[0], e[1], e[2], e[3]);
    h4[1] = make_int4(e[4], e[5], e[6], e[7]);
    __syncthreads();   // spfx + flags-zero visible block-wide

    if (tid < R_) {
        const int pos = tid;
        const int fgn = scnt[0], bgn = scnt[1];
        const bool both    = (fgn > 0) && (bgn > 0);
        const bool only_fg = (fgn > 0) && (bgn == 0);
        const int fg_this  = both ? min(FGP, fgn) : (only_fg ? R_ : 0);
        const bool is_fg   = pos < fg_this;
        int cls, rank, cnum;
        if (is_fg) {
            cls = 0; cnum = fgn;
            if (only_fg) {
                float uf = u_fg[bb * R_ + pos];
                int kk = (int)(uf * (float)fgn);       // trunc toward zero
                rank = min(max(kk, 0), max(fgn - 1, 0));
            } else {
                rank = pos;
            }
        } else {
            cls = 1; cnum = bgn;
            float ubv = u_bg[bb * R_ + pos];
            int kk = (int)(ubv * (float)bgn);
            rank = min(max(kk, 0), max(bgn - 1, 0));
        }
        int4 p4 = make_int4(0, 0, 0, is_fg ? 1 : 0);   // cnum==0 sentinel
        if (cnum > 0) {
            const int* P = spfx[cls];
            int lo = 0, hi = NB_ - 1;
            while (lo < hi) {              // max j with P[j] <= rank
                int mid = (lo + hi + 1) >> 1;
                if (P[mid] <= rank) lo = mid; else hi = mid - 1;
            }
            const int start = P[lo];
            const int next  = (lo < NB_ - 1) ? P[lo + 1] : cnum;
            atomicOr(&flags[(bb * 2 + cls) * FW_ + (lo >> 5)], 1u << (lo & 31));
            p4 = make_int4(start, next - start, rank - start, is_fg ? 1 : 0);
        }
        pick[bb * R_ + pos] = p4;
    }
}

// ---------------------------------------------------------------------------
// K3: scatter ONLY flagged-bucket members; uint4 packed reads (4 rois/thread).
//     Destructive atomicAdd on the prefix is fine: picks carry start/cnt.
// ---------------------------------------------------------------------------
__global__ void scatter_kernel(const unsigned* __restrict__ packed,
                               const unsigned* __restrict__ flags,
                               int*            __restrict__ E,      // hist prefix
                               int*            __restrict__ buckets)
{
    const int b  = blockIdx.y;
    const int i4 = blockIdx.x * blockDim.x + threadIdx.x;
    if (i4 >= M_ / 4) return;
    const uint4 p = ((const uint4*)(packed + (size_t)b * M_))[i4];
    const unsigned pks[4] = { p.x, p.y, p.z, p.w };
    #pragma unroll
    for (int k = 0; k < 4; ++k) {
        unsigned pk = pks[k];
        if (pk == 0xFFFFFFFFu) continue;
        const int cls = (int)(pk >> 16);
        const int bucket = (int)(pk & 0xFFFFu);
        const int row = b * 2 + cls;
        unsigned w = flags[row * FW_ + (bucket >> 5)];     // 16KB table: L2-hot
        if (!(w & (1u << (bucket & 31)))) continue;
        int pp = atomicAdd(&E[(size_t)row * NB_ + bucket], 1);
        buckets[(size_t)row * M_ + pp] = i4 * 4 + k;
    }
}

// ---------------------------------------------------------------------------
// K4: stable (u, idx) rank-selection among bucket members, gather outputs,
//     lazy argmax (reference divide semantics) for picked fg rois only.
//     32 blocks x 64 threads for wider CU coverage of this latency phase.
// ---------------------------------------------------------------------------
__global__ void sample_kernel(const float* __restrict__ all_rois,
                              const float* __restrict__ gt_boxes,
                              const float4* __restrict__ gt4,
                              const float*  __restrict__ garea,
                              const float* __restrict__ u_perm,
                              const int4* __restrict__ pick,
                              const int*  __restrict__ buckets,
                              float*      __restrict__ out)
{
    const int b   = blockIdx.x >> 1;
    const int pos = ((blockIdx.x & 1) << 6) | threadIdx.x;   // 0..127
    const int4 pk = pick[b * R_ + pos];
    const bool is_fg = pk.w != 0;
    const int  cls   = is_fg ? 0 : 1;

    int keep = 0;                  // cnum==0 edge: argsort(all 2.0)[0] == 0
    if (pk.y > 0) {
        const int row = b * 2 + cls;
        const int*   be = buckets + (size_t)row * M_ + pk.x;
        const float* up = u_perm + (size_t)b * M_;
        const int cnt2 = pk.y, r = pk.z;
        for (int t2 = 0; t2 < cnt2; ++t2) {   // r-th smallest by (u, idx)
            int it = be[t2]; float ut = up[it];
            int rk = 0;
            for (int s2 = 0; s2 < cnt2; ++s2) {
                if (s2 == t2) continue;
                int is2 = be[s2]; float us = up[is2];
                if (us < ut || (us == ut && is2 < it)) rk++;
            }
            if (rk == r) { keep = it; break; }
        }
    }

    float ox1, oy1, ox2, oy2;
    if (keep < N_) {
        const float* p = all_rois + ((size_t)b * N_ + keep) * 5;
        ox1 = p[1]; oy1 = p[2]; ox2 = p[3]; oy2 = p[4];
    } else {
        const float* p = gt_boxes + (b * G_ + (keep - N_)) * 6;
        ox1 = p[0]; oy1 = p[1]; ox2 = p[2]; oy2 = p[3];
    }
    float* ro = out + ((size_t)b * R_ + pos) * 5;
    ro[0] = (float)b; ro[1] = ox1; ro[2] = oy1; ro[3] = ox2; ro[4] = oy2;

    float lab = 0.0f, tidv = -1.0f;
    if (is_fg) {
        float aw = ox2 - ox1 + 1.0f, ah = oy2 - oy1 + 1.0f;
        float area_a = aw * ah;
        float bestv = -1e30f;
        int   bi    = 0;
        for (int j = 0; j < G_; ++j) {
            const float4 g  = gt4[b * G_ + j];
            const float  ga = garea[b * G_ + j];
            float iw  = fmaxf(fminf(ox2, g.z) - fmaxf(ox1, g.x) + 1.0f, 0.0f);
            float ih2 = fmaxf(fminf(oy2, g.w) - fmaxf(oy1, g.y) + 1.0f, 0.0f);
            float inter = iw * ih2;
            float ov = inter / (area_a + ga - inter);   // IEEE div, ref order
            if (ov > bestv) { bestv = ov; bi = j; }     // first-max
        }
        lab  = gt_boxes[(b * G_ + bi) * 6 + 4];
        tidv = gt_boxes[(b * G_ + bi) * 6 + 5];
    }
    out[(size_t)B_ * R_ * 5 + b * R_ + pos] = lab;
    out[(size_t)B_ * R_ * 5 + (size_t)B_ * R_ + b * R_ + pos] = tidv;
}

// ---------------------------------------------------------------------------
extern "C" void kernel_launch(void* const* d_in, const int* in_sizes, int n_in,
                              void* d_out, int out_size, void* d_ws, size_t ws_size,
                              hipStream_t stream)
{
    const float* all_rois = (const float*)d_in[0];
    const float* gt_boxes = (const float*)d_in[1];
    const float* u_perm   = (const float*)d_in[2];
    const float* u_fg     = (const float*)d_in[3];
    const float* u_bg     = (const float*)d_in[4];
    float* out = (float*)d_out;

    // workspace layout (4B elems); ~13.3 MB. 16B alignment: pick/packed/gt4
    // offsets all multiples of 4 ints.
    int*      hist    = (int*)d_ws;                               // NROW*NB (512K)
    unsigned* flags   = (unsigned*)(hist + (size_t)NROW_ * NB_);  // NROW*FW (16K)
    int4*     pick    = (int4*)(flags + NROW_ * FW_);             // B*R int4
    unsigned* packed  = (unsigned*)(pick + B_ * R_);              // B*M
    int*      buckets = (int*)(packed + (size_t)B_ * M_);         // NROW*M
    float4*   gt4     = (float4*)(buckets + (size_t)NROW_ * M_);  // B*G
    float*    garea   = (float*)(gt4 + B_ * G_);                  // B*G
    int*      jmax    = (int*)(garea + B_ * G_);                  // B

    prep_kernel<<<256, TPB_, 0, stream>>>(gt_boxes, hist, gt4, garea, jmax);

    dim3 grid1((M_ + TPB_ - 1) / TPB_, B_);
    iou_kernel<<<grid1, TPB_, 0, stream>>>(all_rois, gt_boxes, gt4, garea, jmax,
                                           u_perm, packed, hist);
    scanflag_kernel<<<B_, 1024, 0, stream>>>(hist, flags, u_fg, u_bg, pick);

    dim3 grid3((M_ / 4 + TPB_ - 1) / TPB_, B_);
    scatter_kernel<<<grid3, TPB_, 0, stream>>>(packed, flags, hist, buckets);
    sample_kernel<<<B_ * 2, 64, 0, stream>>>(all_rois, gt_boxes, gt4, garea,
                                             u_perm, pick, buckets, out);
}

// Round 12
// 101.775 us; speedup vs baseline: 2.1337x; 2.1337x over previous
//
#include <hip/hip_runtime.h>

// Problem constants (match reference)
#define B_   16
#define N_   65536
#define G_   64
#define M_   (N_ + G_)       // 65600 rois per batch
#define R_   128             // ROIS_PER_IMAGE
#define FGP  32              // FG_PER_IMAGE
#define NB_  16384           // buckets over u_perm in [0,1): lambda ~= 3.7 bg
#define NCH_ 32              // coarse chunks per row
#define CHUNK_ (NB_ / NCH_)  // 512
#define NROW_ 32             // (batch, class) rows
#define FW_  (NB_ / 32)      // flag words per row = 512
#define TPB_  256

// ---------------------------------------------------------------------------
// K0: zero hist+flags (contiguous); GT table (poisoned gt_zero rows) + jmax.
// ---------------------------------------------------------------------------
__global__ void prep_kernel(const float* __restrict__ gt_boxes,
                            int*    __restrict__ zbase,   // hist..flags
                            float4* __restrict__ gt4,
                            float*  __restrict__ garea,
                            int*    __restrict__ jmax)
{
    const int gid = blockIdx.x * blockDim.x + threadIdx.x;
    const int total = NROW_ * NB_ + NROW_ * FW_;
    for (int idx = gid; idx < total; idx += gridDim.x * blockDim.x) zbase[idx] = 0;
    if (gid < B_ * G_) {
        int b = gid >> 6, j = gid & 63;
        const float* g = gt_boxes + gid * 6;
        float x1 = g[0], y1 = g[1], x2 = g[2], y2 = g[3];
        float gw = x2 - x1 + 1.0f, gh = y2 - y1 + 1.0f;
        bool gz = (gw == 1.0f) && (gh == 1.0f);
        gt4[gid] = gz ? make_float4(3.0e8f, 3.0e8f, -3.0e8f, -3.0e8f)
                      : make_float4(x1, y1, x2, y2);
        garea[gid] = gw * gh;                     // == 1.0 for gz rows
        unsigned long long alive = __ballot(!gz); // lane == j
        if (j == 0) { int last = 63 - __clzll(alive); jmax[b] = (last + 8) & ~7; }
    }
}

// ---------------------------------------------------------------------------
// K1: per-roi rational IoU max. Track (ib, sb) with s = (area_a + ga);
//     cross-product predicate i1*s2 > i2*s1 decided EXACTLY via Dekker
//     two-product lex compare (fl monotone + exact FMA residual).
//     Final best = ib/(sb-ib) reproduces the reference association bit-exactly.
//     One IEEE divide per thread.  (proven: R10 passed absmax 0)
// ---------------------------------------------------------------------------
__global__ void iou_kernel(const float* __restrict__ all_rois,
                           const float* __restrict__ gt_boxes,
                           const float4* __restrict__ gt4,
                           const float*  __restrict__ garea,
                           const int*    __restrict__ jmax,
                           const float*  __restrict__ u_perm,
                           unsigned*     __restrict__ packed,
                           int*          __restrict__ hist)
{
    __shared__ float4 sg[G_];
    __shared__ float  sa[G_];
    const int b   = blockIdx.y;
    const int tid = threadIdx.x;
    if (tid < G_) { sg[tid] = gt4[b * G_ + tid]; sa[tid] = garea[b * G_ + tid]; }
    __syncthreads();

    const int i = blockIdx.x * blockDim.x + tid;
    if (i >= M_) return;

    float x1, y1, x2, y2;
    if (i < N_) {
        const float* p = all_rois + ((size_t)b * N_ + i) * 5;
        x1 = p[1]; y1 = p[2]; x2 = p[3]; y2 = p[4];
    } else {
        const float* p = gt_boxes + (b * G_ + (i - N_)) * 6;
        x1 = p[0]; y1 = p[1]; x2 = p[2]; y2 = p[3];
    }
    float aw = x2 - x1 + 1.0f, ah = y2 - y1 + 1.0f;
    float area_a = aw * ah;
    bool  a_zero = (aw == 1.0f) && (ah == 1.0f);

    const int jm = jmax[b];
    float ib = 0.0f, sb = 1.0f;              // rational best t = 0/1
    for (int jj = 0; jj < jm; jj += 8) {
        #pragma unroll
        for (int kk = 0; kk < 8; ++kk) {
            const int j = jj + kk;
            const float4 g  = sg[j];
            const float  ga = sa[j];
            float iw  = fmaxf(fminf(x2, g.z) - fmaxf(x1, g.x) + 1.0f, 0.0f);
            float ih2 = fmaxf(fminf(y2, g.w) - fmaxf(y1, g.y) + 1.0f, 0.0f);
            float inter = iw * ih2;
            float s     = area_a + ga;
            float hi1 = inter * sb, lo1 = fmaf(inter, sb, -hi1);
            float hi2 = ib * s,     lo2 = fmaf(ib, s, -hi2);
            bool gt = (hi1 > hi2) || ((hi1 == hi2) && (lo1 > lo2));  // exact
            if (gt) { ib = inter; sb = s; }           // strict >: first wins
        }
    }
    float best = ib / (sb - ib);  // ref order: fl(fl(area_a+ga)-inter), then div
    if (a_zero) best = -1.0f;

    bool fg = best >= 0.7f;
    bool bg = best < 0.3f;        // == ((mo<0.3)&(mo>=0)) | (mo<0)
    unsigned pk = 0xFFFFFFFFu;
    if (fg || bg) {
        int cls = fg ? 0 : 1;
        float u = u_perm[(size_t)b * M_ + i];
        int bucket = min(max((int)(u * (float)NB_), 0), NB_ - 1);
        pk = ((unsigned)cls << 16) | (unsigned)bucket;
        atomicAdd(&hist[(size_t)(b * 2 + cls) * NB_ + bucket], 1);
    }
    packed[(size_t)b * M_ + i] = pk;
}

// ---------------------------------------------------------------------------
// K2: 16 blocks x 512 threads (proven R9). Each block exclusive-scans BOTH
//     rows of its batch in place (wave shfl scan; coarse+cnt in LDS), then
//     flags: rank -> bucket via LDS coarse walk + global binsearch, atomicOr
//     flag bit, store {start,cnt,r,is_fg} to pick.
// ---------------------------------------------------------------------------
__global__ __launch_bounds__(512) void scanflag_kernel(
    int*      __restrict__ hist,     // counts -> exclusive prefix (in place)
    unsigned* __restrict__ flags,
    const float* __restrict__ u_fg,
    const float* __restrict__ u_bg,
    int4*     __restrict__ pick)
{
    __shared__ int scoarse[2][NCH_];
    __shared__ int scnt[2];
    __shared__ int swt[2][8], swb[2][8];
    const int bb  = blockIdx.x;       // batch
    const int tid = threadIdx.x;      // 512
    const int lane = tid & 63, w = tid >> 6;

    for (int rr = 0; rr < 2; ++rr) {
        const int row = bb * 2 + rr;
        int4* h4 = (int4*)(hist + (size_t)row * NB_ + tid * 32);
        int v[32];
        #pragma unroll
        for (int q = 0; q < 8; ++q) {
            int4 x4 = h4[q];
            v[q*4] = x4.x; v[q*4+1] = x4.y; v[q*4+2] = x4.z; v[q*4+3] = x4.w;
        }
        int run = 0;
        #pragma unroll
        for (int q = 0; q < 32; ++q) { int x = v[q]; v[q] = run; run += x; }
        int x = run;                                   // wave inclusive scan
        #pragma unroll
        for (int d = 1; d < 64; d <<= 1) {
            int y = __shfl_up(x, d);
            if (lane >= d) x += y;
        }
        if (lane == 63) swt[rr][w] = x;
        __syncthreads();
        if (tid == 0) {
            int a = 0;
            #pragma unroll
            for (int q = 0; q < 8; ++q) { swb[rr][q] = a; a += swt[rr][q]; }
        }
        __syncthreads();
        const int incl  = swb[rr][w] + x;              // thread-inclusive
        const int texcl = incl - run;                  // thread-exclusive base
        #pragma unroll
        for (int q = 0; q < 8; ++q) {
            h4[q] = make_int4(v[q*4] + texcl, v[q*4+1] + texcl,
                              v[q*4+2] + texcl, v[q*4+3] + texcl);
        }
        if ((tid & 15) == 15) scoarse[rr][tid >> 4] = incl;  // 512-bin chunks
        if (tid == 511) scnt[rr] = incl;
    }
    __syncthreads();   // prefix writes + scoarse/scnt visible block-wide

    if (tid < R_) {
        const int pos = tid;
        const int fgn = scnt[0], bgn = scnt[1];
        const bool both    = (fgn > 0) && (bgn > 0);
        const bool only_fg = (fgn > 0) && (bgn == 0);
        const int fg_this  = both ? min(FGP, fgn) : (only_fg ? R_ : 0);
        const bool is_fg   = pos < fg_this;
        int cls, rank, cnum;
        if (is_fg) {
            cls = 0; cnum = fgn;
            if (only_fg) {
                float uf = u_fg[bb * R_ + pos];
                int kk = (int)(uf * (float)fgn);       // trunc toward zero
                rank = min(max(kk, 0), max(fgn - 1, 0));
            } else {
                rank = pos;
            }
        } else {
            cls = 1; cnum = bgn;
            float ubv = u_bg[bb * R_ + pos];
            int kk = (int)(ubv * (float)bgn);
            rank = min(max(kk, 0), max(bgn - 1, 0));
        }
        int4 p4 = make_int4(0, 0, 0, is_fg ? 1 : 0);   // cnum==0 sentinel
        if (cnum > 0) {
            const int row = bb * 2 + cls;
            const int* sce = scoarse[cls];
            int c = 0;                     // first chunk with incl > rank
            while (c < NCH_ - 1 && sce[c] <= rank) ++c;
            const int* Er = hist + (size_t)row * NB_;
            int lo = c * CHUNK_, hi = c * CHUNK_ + CHUNK_ - 1;
            while (lo < hi) {              // max j with Er[j] <= rank
                int mid = (lo + hi + 1) >> 1;
                if (Er[mid] <= rank) lo = mid; else hi = mid - 1;
            }
            const int start = Er[lo];
            const int next  = (lo < NB_ - 1) ? Er[lo + 1] : cnum;
            atomicOr(&flags[row * FW_ + (lo >> 5)], 1u << (lo & 31));
            p4 = make_int4(start, next - start, rank - start, is_fg ? 1 : 0);
        }
        pick[bb * R_ + pos] = p4;
    }
}

// ---------------------------------------------------------------------------
// K3: scatter ONLY flagged-bucket members; uint4 packed reads (4 rois/thread).
//     Destructive atomicAdd on the prefix is fine: picks carry start/cnt.
// ---------------------------------------------------------------------------
__global__ void scatter_kernel(const unsigned* __restrict__ packed,
                               const unsigned* __restrict__ flags,
                               int*            __restrict__ E,      // hist prefix
                               int*            __restrict__ buckets)
{
    const int b  = blockIdx.y;
    const int i4 = blockIdx.x * blockDim.x + threadIdx.x;
    if (i4 >= M_ / 4) return;
    const uint4 p = ((const uint4*)(packed + (size_t)b * M_))[i4];
    const unsigned pks[4] = { p.x, p.y, p.z, p.w };
    #pragma unroll
    for (int k = 0; k < 4; ++k) {
        unsigned pk = pks[k];
        if (pk == 0xFFFFFFFFu) continue;
        const int cls = (int)(pk >> 16);
        const int bucket = (int)(pk & 0xFFFFu);
        const int row = b * 2 + cls;
        unsigned w = flags[row * FW_ + (bucket >> 5)];     // 64KB table: L2-hot
        if (!(w & (1u << (bucket & 31)))) continue;
        int pp = atomicAdd(&E[(size_t)row * NB_ + bucket], 1);
        buckets[(size_t)row * M_ + pp] = i4 * 4 + k;
    }
}

// ---------------------------------------------------------------------------
// K4: stable (u, idx) rank-selection among bucket members, gather outputs,
//     lazy argmax (reference divide semantics) for picked fg rois only.
// ---------------------------------------------------------------------------
__global__ void sample_kernel(const float* __restrict__ all_rois,
                              const float* __restrict__ gt_boxes,
                              const float4* __restrict__ gt4,
                              const float*  __restrict__ garea,
                              const float* __restrict__ u_perm,
                              const int4* __restrict__ pick,
                              const int*  __restrict__ buckets,
                              float*      __restrict__ out)
{
    const int b   = blockIdx.x;
    const int pos = threadIdx.x;   // 128
    const int4 pk = pick[b * R_ + pos];
    const bool is_fg = pk.w != 0;
    const int  cls   = is_fg ? 0 : 1;

    int keep = 0;                  // cnum==0 edge: argsort(all 2.0)[0] == 0
    if (pk.y > 0) {
        const int row = b * 2 + cls;
        const int*   be = buckets + (size_t)row * M_ + pk.x;
        const float* up = u_perm + (size_t)b * M_;
        const int cnt2 = pk.y, r = pk.z;
        for (int t2 = 0; t2 < cnt2; ++t2) {   // r-th smallest by (u, idx)
            int it = be[t2]; float ut = up[it];
            int rk = 0;
            for (int s2 = 0; s2 < cnt2; ++s2) {
                if (s2 == t2) continue;
                int is2 = be[s2]; float us = up[is2];
                if (us < ut || (us == ut && is2 < it)) rk++;
            }
            if (rk == r) { keep = it; break; }
        }
    }

    float ox1, oy1, ox2, oy2;
    if (keep < N_) {
        const float* p = all_rois + ((size_t)b * N_ + keep) * 5;
        ox1 = p[1]; oy1 = p[2]; ox2 = p[3]; oy2 = p[4];
    } else {
        const float* p = gt_boxes + (b * G_ + (keep - N_)) * 6;
        ox1 = p[0]; oy1 = p[1]; ox2 = p[2]; oy2 = p[3];
    }
    float* ro = out + ((size_t)b * R_ + pos) * 5;
    ro[0] = (float)b; ro[1] = ox1; ro[2] = oy1; ro[3] = ox2; ro[4] = oy2;

    float lab = 0.0f, tidv = -1.0f;
    if (is_fg) {
        float aw = ox2 - ox1 + 1.0f, ah = oy2 - oy1 + 1.0f;
        float area_a = aw * ah;
        float bestv = -1e30f;
        int   bi    = 0;
        for (int j = 0; j < G_; ++j) {
            const float4 g  = gt4[b * G_ + j];
            const float  ga = garea[b * G_ + j];
            float iw  = fmaxf(fminf(ox2, g.z) - fmaxf(ox1, g.x) + 1.0f, 0.0f);
            float ih2 = fmaxf(fminf(oy2, g.w) - fmaxf(oy1, g.y) + 1.0f, 0.0f);
            float inter = iw * ih2;
            float ov = inter / (area_a + ga - inter);   // IEEE div, ref order
            if (ov > bestv) { bestv = ov; bi = j; }     // first-max
        }
        lab  = gt_boxes[(b * G_ + bi) * 6 + 4];
        tidv = gt_boxes[(b * G_ + bi) * 6 + 5];
    }
    out[(size_t)B_ * R_ * 5 + b * R_ + pos] = lab;
    out[(size_t)B_ * R_ * 5 + (size_t)B_ * R_ + b * R_ + pos] = tidv;
}

// ---------------------------------------------------------------------------
extern "C" void kernel_launch(void* const* d_in, const int* in_sizes, int n_in,
                              void* d_out, int out_size, void* d_ws, size_t ws_size,
                              hipStream_t stream)
{
    const float* all_rois = (const float*)d_in[0];
    const float* gt_boxes = (const float*)d_in[1];
    const float* u_perm   = (const float*)d_in[2];
    const float* u_fg     = (const float*)d_in[3];
    const float* u_bg     = (const float*)d_in[4];
    float* out = (float*)d_out;

    // workspace layout (4B elems); ~15 MB. hist+flags contiguous (zeroed in
    // prep). pick/packed/gt4 offsets 16B-aligned.
    int*      hist    = (int*)d_ws;                               // NROW*NB (2MB)
    unsigned* flags   = (unsigned*)(hist + (size_t)NROW_ * NB_);  // NROW*FW (64KB)
    int4*     pick    = (int4*)(flags + NROW_ * FW_);             // B*R int4
    unsigned* packed  = (unsigned*)(pick + B_ * R_);              // B*M
    int*      buckets = (int*)(packed + (size_t)B_ * M_);         // NROW*M
    float4*   gt4     = (float4*)(buckets + (size_t)NROW_ * M_);  // B*G
    float*    garea   = (float*)(gt4 + B_ * G_);                  // B*G
    int*      jmax    = (int*)(garea + B_ * G_);                  // B

    prep_kernel<<<512, TPB_, 0, stream>>>(gt_boxes, hist, gt4, garea, jmax);

    dim3 grid1((M_ + TPB_ - 1) / TPB_, B_);
    iou_kernel<<<grid1, TPB_, 0, stream>>>(all_rois, gt_boxes, gt4, garea, jmax,
                                           u_perm, packed, hist);
    scanflag_kernel<<<B_, 512, 0, stream>>>(hist, flags, u_fg, u_bg, pick);

    dim3 grid3((M_ / 4 + TPB_ - 1) / TPB_, B_);
    scatter_kernel<<<grid3, TPB_, 0, stream>>>(packed, flags, hist, buckets);
    sample_kernel<<<B_, R_, 0, stream>>>(all_rois, gt_boxes, gt4, garea,
                                         u_perm, pick, buckets, out);
}